// Round 1
// baseline (993.335 us; speedup 1.0000x reference)
//
#include <hip/hip_runtime.h>
#include <hip/hip_bf16.h>

#define E_ 8
#define D_ 1024
#define F_ 4096
#define G_ 2048

typedef __attribute__((ext_vector_type(8))) short bf16x8;
typedef __attribute__((ext_vector_type(4))) float f32x4;
typedef __attribute__((ext_vector_type(8))) unsigned short u16x8;
typedef unsigned short u16;
typedef unsigned int u32;

// round-to-nearest-even fp32 -> bf16 (branchless)
__device__ __forceinline__ u16 f2bf(float f) {
  u32 u = __float_as_uint(f);
  u = (u + 0x7fffu + ((u >> 16) & 1u)) >> 16;
  return (u16)u;
}

// async global->LDS, 16B per lane; LDS dest = base + lane*16 (wave-uniform base)
__device__ __forceinline__ void gld_lds16(const void* g, void* l) {
  __builtin_amdgcn_global_load_lds(
      (const __attribute__((address_space(1))) u32*)g,
      (__attribute__((address_space(3))) u32*)l, 16, 0, 0);
}

// ---------------- elementwise fp32 -> bf16 ----------------
__global__ __launch_bounds__(256) void k_cvt(const float* __restrict__ in,
                                             u16* __restrict__ out, int n8) {
  int i = blockIdx.x * 256 + threadIdx.x;
  if (i >= n8) return;
  const float4* p = (const float4*)in + (size_t)i * 2;
  float4 a = p[0], b = p[1];
  u16x8 o;
  o[0] = f2bf(a.x); o[1] = f2bf(a.y); o[2] = f2bf(a.z); o[3] = f2bf(a.w);
  o[4] = f2bf(b.x); o[5] = f2bf(b.y); o[6] = f2bf(b.z); o[7] = f2bf(b.w);
  *(u16x8*)(out + (size_t)i * 8) = o;
}

// ---------------- transpose + convert: in [B][R][C] fp32 -> out [B][C][R] bf16 ----
__global__ __launch_bounds__(256) void k_tcvt(const float* __restrict__ in,
                                              u16* __restrict__ out, int R, int C) {
  __shared__ float t[32][33];
  size_t base = (size_t)blockIdx.z * (size_t)R * (size_t)C;
  in += base; out += base;
  int c0 = blockIdx.x * 32, r0 = blockIdx.y * 32;
  int tx = threadIdx.x, ty = threadIdx.y;  // 32 x 8
#pragma unroll
  for (int j = 0; j < 32; j += 8)
    t[ty + j][tx] = in[(size_t)(r0 + ty + j) * C + (c0 + tx)];
  __syncthreads();
#pragma unroll
  for (int j = 0; j < 32; j += 8)
    out[(size_t)(c0 + ty + j) * R + (r0 + tx)] = f2bf(t[tx][ty + j]);
}

// ---------------- fused GEMM1+GEMM2 + SwiGLU ----------------
// middle = X@W1, gate = X@W2, H = silu(middle)*gate   (per expert)
// X: [G,D] bf16 row-major; W1t/W2t: [F,D] bf16 (k=d contiguous); H: [G,F] bf16
// tile: BM=128, BN=64, BK=32; 4 waves in 2x2, each wave 64x32 per GEMM
__global__ __launch_bounds__(256) void k_mlp1(const u16* __restrict__ X,
                                              const u16* __restrict__ W1t,
                                              const u16* __restrict__ W2t,
                                              u16* __restrict__ H) {
  __shared__ __align__(16) u16 As[128 * 32];   // 8KB
  __shared__ __align__(16) u16 B1s[64 * 32];   // 4KB
  __shared__ __align__(16) u16 B2s[64 * 32];   // 4KB
  const int e = blockIdx.z;
  const u16* A  = X   + (size_t)e * G_ * D_;
  const u16* B1 = W1t + (size_t)e * F_ * D_;
  const u16* B2 = W2t + (size_t)e * F_ * D_;
  u16* Hp = H + (size_t)e * G_ * F_;
  const int bm = blockIdx.y * 128, bn = blockIdx.x * 64;
  const int tid = threadIdx.x, wave = tid >> 6, lane = tid & 63;
  const int wm = (wave >> 1) * 64, wn = (wave & 1) * 32;
  const int quad = lane >> 4, l16 = lane & 15;

  // staging: chunk = 512 elems = 1KB; lane elem = chunk*512 + lane*8
  const int ea0 = wave * 512 + lane * 8;
  const int ea1 = (wave + 4) * 512 + lane * 8;
  const int ra0 = ea0 >> 5, ca0 = ea0 & 31;
  const int ra1 = ea1 >> 5, ca1 = ea1 & 31;

  f32x4 acc1[4][2], acc2[4][2];
#pragma unroll
  for (int i = 0; i < 4; i++)
#pragma unroll
    for (int j = 0; j < 2; j++) {
      acc1[i][j] = f32x4{0.f, 0.f, 0.f, 0.f};
      acc2[i][j] = f32x4{0.f, 0.f, 0.f, 0.f};
    }

  for (int k0 = 0; k0 < D_; k0 += 32) {
    gld_lds16(A  + (size_t)(bm + ra0) * D_ + k0 + ca0, (char*)As  + wave * 1024);
    gld_lds16(A  + (size_t)(bm + ra1) * D_ + k0 + ca1, (char*)As  + (wave + 4) * 1024);
    gld_lds16(B1 + (size_t)(bn + ra0) * D_ + k0 + ca0, (char*)B1s + wave * 1024);
    gld_lds16(B2 + (size_t)(bn + ra0) * D_ + k0 + ca0, (char*)B2s + wave * 1024);
    __syncthreads();
    bf16x8 af[4], b1f[2], b2f[2];
#pragma unroll
    for (int i = 0; i < 4; i++)
      af[i] = *(const bf16x8*)(As + (wm + i * 16 + l16) * 32 + quad * 8);
#pragma unroll
    for (int j = 0; j < 2; j++) {
      b1f[j] = *(const bf16x8*)(B1s + (wn + j * 16 + l16) * 32 + quad * 8);
      b2f[j] = *(const bf16x8*)(B2s + (wn + j * 16 + l16) * 32 + quad * 8);
    }
#pragma unroll
    for (int i = 0; i < 4; i++)
#pragma unroll
      for (int j = 0; j < 2; j++) {
        acc1[i][j] = __builtin_amdgcn_mfma_f32_16x16x32_bf16(af[i], b1f[j], acc1[i][j], 0, 0, 0);
        acc2[i][j] = __builtin_amdgcn_mfma_f32_16x16x32_bf16(af[i], b2f[j], acc2[i][j], 0, 0, 0);
      }
    __syncthreads();
  }
  // epilogue: SwiGLU, store bf16
#pragma unroll
  for (int i = 0; i < 4; i++)
#pragma unroll
    for (int j = 0; j < 2; j++)
#pragma unroll
      for (int r = 0; r < 4; r++) {
        float m = acc1[i][j][r], g = acc2[i][j][r];
        float h = (m / (1.f + __expf(-m))) * g;  // silu(m)*g
        int row = bm + wm + i * 16 + quad * 4 + r;
        int col = bn + wn + j * 16 + l16;
        Hp[(size_t)row * F_ + col] = f2bf(h);
      }
}

// ---------------- GEMM3: out = H @ W3 ----------------
// H: [G,F] bf16; W3t: [D,F] bf16 (k=f contiguous); out: [G,D] fp32
// tile: BM=128, BN=128, BK=32; 4 waves 2x2, each wave 64x64
__global__ __launch_bounds__(256) void k_mlp2(const u16* __restrict__ H,
                                              const u16* __restrict__ W3t,
                                              float* __restrict__ O) {
  __shared__ __align__(16) u16 As[128 * 32];  // 8KB
  __shared__ __align__(16) u16 Bs[128 * 32];  // 8KB
  const int e = blockIdx.z;
  const u16* A = H   + (size_t)e * G_ * F_;
  const u16* B = W3t + (size_t)e * D_ * F_;
  float* C = O + (size_t)e * G_ * D_;
  const int bm = blockIdx.y * 128, bn = blockIdx.x * 128;
  const int tid = threadIdx.x, wave = tid >> 6, lane = tid & 63;
  const int wm = (wave >> 1) * 64, wn = (wave & 1) * 64;
  const int quad = lane >> 4, l16 = lane & 15;

  const int ea0 = wave * 512 + lane * 8;
  const int ea1 = (wave + 4) * 512 + lane * 8;
  const int ra0 = ea0 >> 5, ca0 = ea0 & 31;
  const int ra1 = ea1 >> 5, ca1 = ea1 & 31;

  f32x4 acc[4][4];
#pragma unroll
  for (int i = 0; i < 4; i++)
#pragma unroll
    for (int j = 0; j < 4; j++) acc[i][j] = f32x4{0.f, 0.f, 0.f, 0.f};

  for (int k0 = 0; k0 < F_; k0 += 32) {
    gld_lds16(A + (size_t)(bm + ra0) * F_ + k0 + ca0, (char*)As + wave * 1024);
    gld_lds16(A + (size_t)(bm + ra1) * F_ + k0 + ca1, (char*)As + (wave + 4) * 1024);
    gld_lds16(B + (size_t)(bn + ra0) * F_ + k0 + ca0, (char*)Bs + wave * 1024);
    gld_lds16(B + (size_t)(bn + ra1) * F_ + k0 + ca1, (char*)Bs + (wave + 4) * 1024);
    __syncthreads();
    bf16x8 af[4], bf[4];
#pragma unroll
    for (int i = 0; i < 4; i++) {
      af[i] = *(const bf16x8*)(As + (wm + i * 16 + l16) * 32 + quad * 8);
      bf[i] = *(const bf16x8*)(Bs + (wn + i * 16 + l16) * 32 + quad * 8);
    }
#pragma unroll
    for (int i = 0; i < 4; i++)
#pragma unroll
      for (int j = 0; j < 4; j++)
        acc[i][j] = __builtin_amdgcn_mfma_f32_16x16x32_bf16(af[i], bf[j], acc[i][j], 0, 0, 0);
    __syncthreads();
  }
#pragma unroll
  for (int i = 0; i < 4; i++)
#pragma unroll
    for (int j = 0; j < 4; j++)
#pragma unroll
      for (int r = 0; r < 4; r++) {
        int row = bm + wm + i * 16 + quad * 4 + r;
        int col = bn + wn + j * 16 + l16;
        C[(size_t)row * D_ + col] = acc[i][j][r];
      }
}

extern "C" void kernel_launch(void* const* d_in, const int* in_sizes, int n_in,
                              void* d_out, int out_size, void* d_ws, size_t ws_size,
                              hipStream_t stream) {
  const float* x  = (const float*)d_in[0];  // [E*G, D]
  const float* w1 = (const float*)d_in[1];  // [E*D, F]
  const float* w2 = (const float*)d_in[2];  // [E*D, F]
  const float* w3 = (const float*)d_in[3];  // [E*F, D]
  float* out = (float*)d_out;               // [E*G, D] fp32
  char* ws = (char*)d_ws;

  // workspace layout (288MB total):
  //   Xb  [0,   32MB)  bf16 [E][G][D]     (dead after k_mlp1)
  //   W1t [32,  96MB)  bf16 [E][F][D]     (dead after k_mlp1)
  //   W2t [96, 160MB)  bf16 [E][F][D]     (dead after k_mlp1)
  //   Hb  [160,288MB)  bf16 [E][G][F]
  //   W3t [0,   64MB)  bf16 [E][D][F]     (written AFTER k_mlp1; aliases Xb/W1t-head)
  u16* Xb  = (u16*)(ws);
  u16* W1t = (u16*)(ws + (size_t)32 * 1024 * 1024);
  u16* W2t = (u16*)(ws + (size_t)96 * 1024 * 1024);
  u16* Hb  = (u16*)(ws + (size_t)160 * 1024 * 1024);
  u16* W3t = (u16*)(ws);

  // 1) X fp32->bf16
  k_cvt<<<dim3((E_ * G_ * D_ / 8 + 255) / 256), dim3(256), 0, stream>>>(
      x, Xb, E_ * G_ * D_ / 8);
  // 2) W1,W2: [D,F] -> [F,D] bf16
  k_tcvt<<<dim3(F_ / 32, D_ / 32, E_), dim3(32, 8, 1), 0, stream>>>(w1, W1t, D_, F_);
  k_tcvt<<<dim3(F_ / 32, D_ / 32, E_), dim3(32, 8, 1), 0, stream>>>(w2, W2t, D_, F_);
  // 3) hidden = silu(X@W1) * (X@W2)
  k_mlp1<<<dim3(F_ / 64, G_ / 128, E_), dim3(256), 0, stream>>>(Xb, W1t, W2t, Hb);
  // 4) W3: [F,D] -> [D,F] bf16 (into region freed by Xb/W1t)
  k_tcvt<<<dim3(D_ / 32, F_ / 32, E_), dim3(32, 8, 1), 0, stream>>>(w3, W3t, F_, D_);
  // 5) out = hidden @ W3
  k_mlp2<<<dim3(D_ / 128, G_ / 128, E_), dim3(256), 0, stream>>>(Hb, W3t, out);
}

// Round 2
// 974.684 us; speedup vs baseline: 1.0191x; 1.0191x over previous
//
#include <hip/hip_runtime.h>
#include <hip/hip_bf16.h>

#define E_ 8
#define D_ 1024
#define F_ 4096
#define G_ 2048

typedef __attribute__((ext_vector_type(8))) short bf16x8;
typedef __attribute__((ext_vector_type(4))) float f32x4;
typedef __attribute__((ext_vector_type(8))) unsigned short u16x8;
typedef unsigned short u16;
typedef unsigned int u32;

// round-to-nearest-even fp32 -> bf16 (branchless)
__device__ __forceinline__ u16 f2bf(float f) {
  u32 u = __float_as_uint(f);
  u = (u + 0x7fffu + ((u >> 16) & 1u)) >> 16;
  return (u16)u;
}

// async global->LDS, 16B per lane; LDS dest = base + lane*16 (wave-uniform base)
__device__ __forceinline__ void gld_lds16(const void* g, void* l) {
  __builtin_amdgcn_global_load_lds(
      (const __attribute__((address_space(1))) u32*)g,
      (__attribute__((address_space(3))) u32*)l, 16, 0, 0);
}

// ---------------- elementwise fp32 -> bf16 ----------------
__global__ __launch_bounds__(256) void k_cvt(const float* __restrict__ in,
                                             u16* __restrict__ out, int n8) {
  int i = blockIdx.x * 256 + threadIdx.x;
  if (i >= n8) return;
  const float4* p = (const float4*)in + (size_t)i * 2;
  float4 a = p[0], b = p[1];
  u16x8 o;
  o[0] = f2bf(a.x); o[1] = f2bf(a.y); o[2] = f2bf(a.z); o[3] = f2bf(a.w);
  o[4] = f2bf(b.x); o[5] = f2bf(b.y); o[6] = f2bf(b.z); o[7] = f2bf(b.w);
  *(u16x8*)(out + (size_t)i * 8) = o;
}

// ---- transpose+convert: in [B][R][C] fp32 -> out [B][C][R] bf16, 64x64 tiles ----
// load: float4 coalesced (256B/16-lane row); store: bf16x8 (128B segments).
// LDS: bf16 [64][72] padded (stride 144B keeps 16B alignment, breaks pow2 banks).
__global__ __launch_bounds__(256) void k_tcvt(const float* __restrict__ in,
                                              u16* __restrict__ out, int R, int C) {
  __shared__ __align__(16) u16 Tt[64 * 72];
  size_t base = (size_t)blockIdx.z * (size_t)R * (size_t)C;
  in += base; out += base;
  const int c0 = blockIdx.x * 64, r0 = blockIdx.y * 64;
  const int tid = threadIdx.x;
  {
    const int cq = tid & 15, rr = tid >> 4;  // 16 float4-cols x 16 rows
    const float* ip = in + (size_t)(r0 + rr) * C + c0 + cq * 4;
#pragma unroll
    for (int i = 0; i < 4; i++) {
      float4 v = *(const float4*)(ip + (size_t)(16 * i) * C);
      const int r = rr + 16 * i, c = cq * 4;
      Tt[(c + 0) * 72 + r] = f2bf(v.x);
      Tt[(c + 1) * 72 + r] = f2bf(v.y);
      Tt[(c + 2) * 72 + r] = f2bf(v.z);
      Tt[(c + 3) * 72 + r] = f2bf(v.w);
    }
  }
  __syncthreads();
  {
    const int rq = tid & 7, cc0 = tid >> 3;  // 8x (8 bf16) x 32 out-rows
#pragma unroll
    for (int i = 0; i < 2; i++) {
      const int cc = cc0 + 32 * i;
      u16x8 v = *(const u16x8*)(Tt + cc * 72 + rq * 8);
      *(u16x8*)(out + (size_t)(c0 + cc) * R + r0 + rq * 8) = v;
    }
  }
}

// ---------------- fused GEMM1+GEMM2 + SwiGLU ----------------
// middle = X@W1, gate = X@W2, H = silu(middle)*gate   (per expert)
// X: [G,D] bf16 row-major; W1t/W2t: [F,D] bf16 (k=d contiguous); H: [G,F] bf16
// tile: BM=128, BN=64, BK=32; 4 waves in 2x2, each wave 64x32 per GEMM
// LDS XOR-swizzle: slot (row, qs) holds global 8-group (row, qs ^ ((row>>1)&3))
// -> ds_read_b128 fragment reads are bank-conflict-free (8 distinct 4-bank groups
//    per 8 consecutive lanes) with zero extra inner-loop instructions.
__global__ __launch_bounds__(256) void k_mlp1(const u16* __restrict__ X,
                                              const u16* __restrict__ W1t,
                                              const u16* __restrict__ W2t,
                                              u16* __restrict__ H) {
  __shared__ __align__(16) u16 As[128 * 32];   // 8KB
  __shared__ __align__(16) u16 B1s[64 * 32];   // 4KB
  __shared__ __align__(16) u16 B2s[64 * 32];   // 4KB
  const int e = blockIdx.z;
  const u16* A  = X   + (size_t)e * G_ * D_;
  const u16* B1 = W1t + (size_t)e * F_ * D_;
  const u16* B2 = W2t + (size_t)e * F_ * D_;
  u16* Hp = H + (size_t)e * G_ * F_;
  const int bm = blockIdx.y * 128, bn = blockIdx.x * 64;
  const int tid = threadIdx.x, wave = tid >> 6, lane = tid & 63;
  const int wm = (wave >> 1) * 64, wn = (wave & 1) * 32;
  const int quad = lane >> 4, l16 = lane & 15;

  // staging: chunk = 512 elems = 1KB; lane slot = chunk*512 + lane*8
  const int ea0 = wave * 512 + lane * 8;
  const int ra0 = ea0 >> 5, ra1 = ra0 + 64;
  const int qs0 = (ea0 >> 3) & 3;
  const int ca0 = (qs0 ^ ((ra0 >> 1) & 3)) << 3;  // swizzled global col offset
  // fragment-read swizzle (row = wm+16i+l16 -> (row>>1)&3 == (l16>>1)&3)
  const int fco = ((quad ^ ((l16 >> 1) & 3)) << 3);

  f32x4 acc1[4][2], acc2[4][2];
#pragma unroll
  for (int i = 0; i < 4; i++)
#pragma unroll
    for (int j = 0; j < 2; j++) {
      acc1[i][j] = f32x4{0.f, 0.f, 0.f, 0.f};
      acc2[i][j] = f32x4{0.f, 0.f, 0.f, 0.f};
    }

  for (int k0 = 0; k0 < D_; k0 += 32) {
    gld_lds16(A  + (size_t)(bm + ra0) * D_ + k0 + ca0, (char*)As  + wave * 1024);
    gld_lds16(A  + (size_t)(bm + ra1) * D_ + k0 + ca0, (char*)As  + (wave + 4) * 1024);
    gld_lds16(B1 + (size_t)(bn + ra0) * D_ + k0 + ca0, (char*)B1s + wave * 1024);
    gld_lds16(B2 + (size_t)(bn + ra0) * D_ + k0 + ca0, (char*)B2s + wave * 1024);
    __syncthreads();
    bf16x8 af[4], b1f[2], b2f[2];
#pragma unroll
    for (int i = 0; i < 4; i++)
      af[i] = *(const bf16x8*)(As + (wm + i * 16 + l16) * 32 + fco);
#pragma unroll
    for (int j = 0; j < 2; j++) {
      b1f[j] = *(const bf16x8*)(B1s + (wn + j * 16 + l16) * 32 + fco);
      b2f[j] = *(const bf16x8*)(B2s + (wn + j * 16 + l16) * 32 + fco);
    }
#pragma unroll
    for (int i = 0; i < 4; i++)
#pragma unroll
      for (int j = 0; j < 2; j++) {
        acc1[i][j] = __builtin_amdgcn_mfma_f32_16x16x32_bf16(af[i], b1f[j], acc1[i][j], 0, 0, 0);
        acc2[i][j] = __builtin_amdgcn_mfma_f32_16x16x32_bf16(af[i], b2f[j], acc2[i][j], 0, 0, 0);
      }
    __syncthreads();
  }
  // epilogue: SwiGLU, store bf16
#pragma unroll
  for (int i = 0; i < 4; i++)
#pragma unroll
    for (int j = 0; j < 2; j++)
#pragma unroll
      for (int r = 0; r < 4; r++) {
        float m = acc1[i][j][r], g = acc2[i][j][r];
        float h = (m / (1.f + __expf(-m))) * g;  // silu(m)*g
        int row = bm + wm + i * 16 + quad * 4 + r;
        int col = bn + wn + j * 16 + l16;
        Hp[(size_t)row * F_ + col] = f2bf(h);
      }
}

// ---------------- GEMM3: out = H @ W3 ----------------
// H: [G,F] bf16; W3t: [D,F] bf16 (k=f contiguous); out: [G,D] fp32
// tile: BM=128, BN=128, BK=32; 4 waves 2x2, each wave 64x64. Same LDS swizzle.
__global__ __launch_bounds__(256) void k_mlp2(const u16* __restrict__ H,
                                              const u16* __restrict__ W3t,
                                              float* __restrict__ O) {
  __shared__ __align__(16) u16 As[128 * 32];  // 8KB
  __shared__ __align__(16) u16 Bs[128 * 32];  // 8KB
  const int e = blockIdx.z;
  const u16* A = H   + (size_t)e * G_ * F_;
  const u16* B = W3t + (size_t)e * D_ * F_;
  float* C = O + (size_t)e * G_ * D_;
  const int bm = blockIdx.y * 128, bn = blockIdx.x * 128;
  const int tid = threadIdx.x, wave = tid >> 6, lane = tid & 63;
  const int wm = (wave >> 1) * 64, wn = (wave & 1) * 64;
  const int quad = lane >> 4, l16 = lane & 15;

  const int ea0 = wave * 512 + lane * 8;
  const int ra0 = ea0 >> 5, ra1 = ra0 + 64;
  const int qs0 = (ea0 >> 3) & 3;
  const int ca0 = (qs0 ^ ((ra0 >> 1) & 3)) << 3;
  const int fco = ((quad ^ ((l16 >> 1) & 3)) << 3);

  f32x4 acc[4][4];
#pragma unroll
  for (int i = 0; i < 4; i++)
#pragma unroll
    for (int j = 0; j < 4; j++) acc[i][j] = f32x4{0.f, 0.f, 0.f, 0.f};

  for (int k0 = 0; k0 < F_; k0 += 32) {
    gld_lds16(A + (size_t)(bm + ra0) * F_ + k0 + ca0, (char*)As + wave * 1024);
    gld_lds16(A + (size_t)(bm + ra1) * F_ + k0 + ca0, (char*)As + (wave + 4) * 1024);
    gld_lds16(B + (size_t)(bn + ra0) * F_ + k0 + ca0, (char*)Bs + wave * 1024);
    gld_lds16(B + (size_t)(bn + ra1) * F_ + k0 + ca0, (char*)Bs + (wave + 4) * 1024);
    __syncthreads();
    bf16x8 af[4], bf[4];
#pragma unroll
    for (int i = 0; i < 4; i++) {
      af[i] = *(const bf16x8*)(As + (wm + i * 16 + l16) * 32 + fco);
      bf[i] = *(const bf16x8*)(Bs + (wn + i * 16 + l16) * 32 + fco);
    }
#pragma unroll
    for (int i = 0; i < 4; i++)
#pragma unroll
      for (int j = 0; j < 4; j++)
        acc[i][j] = __builtin_amdgcn_mfma_f32_16x16x32_bf16(af[i], bf[j], acc[i][j], 0, 0, 0);
    __syncthreads();
  }
#pragma unroll
  for (int i = 0; i < 4; i++)
#pragma unroll
    for (int j = 0; j < 4; j++)
#pragma unroll
      for (int r = 0; r < 4; r++) {
        int row = bm + wm + i * 16 + quad * 4 + r;
        int col = bn + wn + j * 16 + l16;
        C[(size_t)row * D_ + col] = acc[i][j][r];
      }
}

extern "C" void kernel_launch(void* const* d_in, const int* in_sizes, int n_in,
                              void* d_out, int out_size, void* d_ws, size_t ws_size,
                              hipStream_t stream) {
  const float* x  = (const float*)d_in[0];  // [E*G, D]
  const float* w1 = (const float*)d_in[1];  // [E*D, F]
  const float* w2 = (const float*)d_in[2];  // [E*D, F]
  const float* w3 = (const float*)d_in[3];  // [E*F, D]
  float* out = (float*)d_out;               // [E*G, D] fp32
  char* ws = (char*)d_ws;

  // workspace layout (288MB total):
  //   Xb  [0,   32MB)  bf16 [E][G][D]     (dead after k_mlp1)
  //   W1t [32,  96MB)  bf16 [E][F][D]     (dead after k_mlp1)
  //   W2t [96, 160MB)  bf16 [E][F][D]     (dead after k_mlp1)
  //   Hb  [160,288MB)  bf16 [E][G][F]
  //   W3t [0,   64MB)  bf16 [E][D][F]     (written AFTER k_mlp1; aliases Xb/W1t-head)
  u16* Xb  = (u16*)(ws);
  u16* W1t = (u16*)(ws + (size_t)32 * 1024 * 1024);
  u16* W2t = (u16*)(ws + (size_t)96 * 1024 * 1024);
  u16* Hb  = (u16*)(ws + (size_t)160 * 1024 * 1024);
  u16* W3t = (u16*)(ws);

  // 1) X fp32->bf16
  k_cvt<<<dim3((E_ * G_ * D_ / 8 + 255) / 256), dim3(256), 0, stream>>>(
      x, Xb, E_ * G_ * D_ / 8);
  // 2) W1,W2: [D,F] -> [F,D] bf16
  k_tcvt<<<dim3(F_ / 64, D_ / 64, E_), dim3(256), 0, stream>>>(w1, W1t, D_, F_);
  k_tcvt<<<dim3(F_ / 64, D_ / 64, E_), dim3(256), 0, stream>>>(w2, W2t, D_, F_);
  // 3) hidden = silu(X@W1) * (X@W2)
  k_mlp1<<<dim3(F_ / 64, G_ / 128, E_), dim3(256), 0, stream>>>(Xb, W1t, W2t, Hb);
  // 4) W3: [F,D] -> [D,F] bf16 (into region freed by Xb/W1t)
  k_tcvt<<<dim3(D_ / 64, F_ / 64, E_), dim3(256), 0, stream>>>(w3, W3t, F_, D_);
  // 5) out = hidden @ W3
  k_mlp2<<<dim3(D_ / 128, G_ / 128, E_), dim3(256), 0, stream>>>(Hb, W3t, out);
}